// Round 20
// baseline (177.108 us; speedup 1.0000x reference)
//
#include <hip/hip_runtime.h>

#define NB 16
#define LT 4096
#define ND 512
#define MBINS 1024
#define LMBDA 0.1f
#define DLB 8                 // d-channels per fwd block
#define FWD_THREADS 1024

__device__ __forceinline__ float2 cmulf(float2 a, float2 b) {
    return make_float2(a.x * b.x - a.y * b.y, a.x * b.y + a.y * b.x);
}
__device__ __forceinline__ float2 caddf(float2 a, float2 b) { return make_float2(a.x + b.x, a.y + b.y); }
__device__ __forceinline__ float2 csubf(float2 a, float2 b) { return make_float2(a.x - b.x, a.y - b.y); }

// base-4 digit reversal of a 10-bit index (bit-reverse, then swap adjacent bit pairs)
__device__ __forceinline__ int rev4_10(int k) {
    unsigned r = __brev((unsigned)k) >> 22;
    return (int)(((r & 0x155u) << 1) | ((r >> 1) & 0x155u));
}
// base-4 digit reversal of a 12-bit index
__device__ __forceinline__ int rev4_12(int t) {
    unsigned r = __brev((unsigned)t) >> 20;
    return (int)(((r & 0x555u) << 1) | ((r >> 1) & 0x555u));
}

// Bijective XOR swizzle on float4-unit index (128B bank window = 8 units).
// Key folds bits 4-12 so the wave-varying address bits (bfm in the m=1 stage,
// rev'd g-digits in the combine) spread accesses across all 8 window slots;
// contiguous runs (stage-1, middle stages) see a constant key per 16-unit run
// -> slot permutation only, stays at the bank floor.
__device__ __forceinline__ int zu4(int u) {
    return u ^ (((u >> 4) ^ (u >> 7) ^ (u >> 10)) & 7);
}

// ws layout: float [4][NB][MBINS] : 0 -> sum|Qa|^2, 1 -> sum|Qb|^2, 2 -> Re C, 3 -> Im C
// where C = sum_d conj(Qa)*Qb.

// Forward: block = (batch, 8 consecutive d), 1024 threads. Real-pack z = a + i*b.
// == R19 champion (173 us) + global zu4 LDS swizzle + const-offset combine ==
//  (a) all z accesses swizzled at float4 granularity: fixes the m=1 stage's
//      4x-floor pattern and the combine's 2x-floor bit-reversed reads.
//  (b) rev4_10(g+128j) = rev4_10(g) + (j>>1) + 8*(j&1): the combine's 16 rev4_10
//      calls/round collapse to 2 per-thread constants + compile-time offsets
//      (mirror: rkg2 + off(7-j), g=0 case off((8-j)&7); verified algebraically).
// Structural constraint (R12-R15 ledger): 64-VGPR allocator ceiling at 1024-thread
// blocks -- occupancy(R12:cliff), conflicts-via-extra-barrier(R13), single-pass
// (R14:L2 granularity), fused-m=1(R15:spill) each cost more than they save.
__global__ __launch_bounds__(FWD_THREADS)
void cte_fwd_kernel(const float* __restrict__ A, const float* __restrict__ Bp,
                    float* __restrict__ ws) {
    __shared__ __align__(16) float2 z[8192];   // 4096 float4 units, via zu4; 64 KB
    __shared__ float2 tw[256];         // tw[e] = exp(-2*pi*i*e/1024), e<256; 2 KB
    __shared__ float2 tw2[512];        // tw2[128*t2+g] = exp(-2*pi*i*(t2*g)/4096); 4 KB

    const int tid = threadIdx.x;
    // XCD-aware swizzle: line-sharing chunk pairs (2c,2c+1) -> same XCD, adjacent slots.
    const int logical = (blockIdx.x & 7) * (gridDim.x >> 3) + (blockIdx.x >> 3);
    const int bb    = logical >> 6;           // 16 batches
    const int chunk = logical & 63;           // 64 d-chunks of 8
    const int d0    = chunk * DLB;

    if (tid < 256) {
        float s, c;
        sincosf(-6.283185307179586f * (float)tid * (1.0f / 1024.0f), &s, &c);
        tw[tid] = make_float2(c, s);
    }
    if (tid < 512) {
        int t2i = tid >> 7, gi = tid & 127;
        float s, c;
        sincosf(-1.5339807878856412e-03f * (float)(t2i * gi), &s, &c);  // -2pi/4096 * t2*g
        tw2[tid] = make_float2(c, s);
    }

    const int dl  = tid & 7;          // d lane
    const int g   = tid >> 3;         // k-group 0..127
    const int dp  = tid & 3;          // d-pair for the load/stage1 phase
    const int t1l = tid >> 2;         // [0,256): stage-1 butterfly row
    const int dp2 = tid & 3;          // col pair for middle stages
    const int bfm = tid >> 2;         // middle-stage butterfly id [0,256)

    const int dl2 = dl >> 1, dlo = dl & 1;   // combine sub-addressing
    const int rkg  = rev4_10(g);             // primary row base (x4 = unit base)
    const int gm   = (128 - g) & 127;
    const int rkg2 = rev4_10(gm);            // mirror row base
    const bool gz  = (g == 0);

    float2 X1[8], Z4[8];              // X[k] and X[(4096-k)%4096], k = g + 128*j
#pragma unroll
    for (int j = 0; j < 8; ++j) {
        X1[j] = make_float2(0.f, 0.f);
        Z4[j] = make_float2(0.f, 0.f);
    }

    for (int t2 = 0; t2 < 4; ++t2) {
        // ---- issue this round's global loads BEFORE the barrier (latency drains
        //      while waiting for the last wave of the previous combine) ----
        float2 A4[4], B4[4];
#pragma unroll
        for (int it = 0; it < 4; ++it) {
            size_t off = ((size_t)(bb * LT + 4 * (t1l + 256 * it) + t2)) * ND + d0 + 2 * dp;
            A4[it] = *(const float2*)(A + off);
            B4[it] = *(const float2*)(Bp + off);
        }

        __syncthreads();  // previous round's combine reads of z done; tw/tw2 valid (rd 0)

        // ---- radix-4 stage 1 (m=256) in registers; swizzled float4 writes ----
        {
            float2 w1 = tw[t1l];
            float2 w2 = cmulf(w1, w1);
            float2 w3 = cmulf(w2, w1);
            float2 T0[2], T1[2], T2[2], T3[2];
#pragma unroll
            for (int c = 0; c < 2; ++c) {
                float2 x0 = c ? make_float2(A4[0].y, B4[0].y) : make_float2(A4[0].x, B4[0].x);
                float2 x1 = c ? make_float2(A4[1].y, B4[1].y) : make_float2(A4[1].x, B4[1].x);
                float2 x2 = c ? make_float2(A4[2].y, B4[2].y) : make_float2(A4[2].x, B4[2].x);
                float2 x3 = c ? make_float2(A4[3].y, B4[3].y) : make_float2(A4[3].x, B4[3].x);
                T0[c] = caddf(x0, x2);  T1[c] = csubf(x0, x2);
                T2[c] = caddf(x1, x3);  T3[c] = csubf(x1, x3);
            }
            const int ub = (t1l << 2) + dp;   // float4 unit index, row t1l
            {   // row +0: y0 = t0 + t2
                float2 ya = caddf(T0[0], T2[0]);
                float2 yb = caddf(T0[1], T2[1]);
                *(float4*)&z[zu4(ub) << 1] = make_float4(ya.x, ya.y, yb.x, yb.y);
            }
            {   // row +256: y1 = (t1 - i*t3) * w1
                float2 ya = cmulf(make_float2(T1[0].x + T3[0].y, T1[0].y - T3[0].x), w1);
                float2 yb = cmulf(make_float2(T1[1].x + T3[1].y, T1[1].y - T3[1].x), w1);
                *(float4*)&z[zu4(ub + 1024) << 1] = make_float4(ya.x, ya.y, yb.x, yb.y);
            }
            {   // row +512: y2 = (t0 - t2) * w2
                float2 ya = cmulf(csubf(T0[0], T2[0]), w2);
                float2 yb = cmulf(csubf(T0[1], T2[1]), w2);
                *(float4*)&z[zu4(ub + 2048) << 1] = make_float4(ya.x, ya.y, yb.x, yb.y);
            }
            {   // row +768: y3 = (t1 + i*t3) * w3
                float2 ya = cmulf(make_float2(T1[0].x - T3[0].y, T1[0].y + T3[0].x), w3);
                float2 yb = cmulf(make_float2(T1[1].x - T3[1].y, T1[1].y + T3[1].x), w3);
                *(float4*)&z[zu4(ub + 3072) << 1] = make_float4(ya.x, ya.y, yb.x, yb.y);
            }
        }
        __syncthreads();

        // ---- remaining radix-4 DIF stages (m = 64,16,4,1): one b128 butterfly/thread ----
        // (m=1: j=0, tw[0]=(1,0) -> generic butterfly is exact; completes the FFT.)
#pragma unroll
        for (int st = 0; st < 4; ++st) {
            const int lgm  = 6 - 2 * st;      // 6,4,2,0
            const int m    = 1 << lgm;
            const int step = 256 >> lgm;      // 1024/(4m)
            int j   = bfm & (m - 1);
            int i0  = ((bfm >> lgm) << (lgm + 2)) + j;
            int u0  = (i0 << 2) + dp2;        // float4 unit; +m rows = +4m units
            int ua  = zu4(u0)          << 1;
            int ub_ = zu4(u0 + 4 * m)  << 1;
            int uc  = zu4(u0 + 8 * m)  << 1;
            int ud  = zu4(u0 + 12 * m) << 1;
            float4 a0 = *(float4*)&z[ua];
            float4 a1 = *(float4*)&z[ub_];
            float4 a2 = *(float4*)&z[uc];
            float4 a3 = *(float4*)&z[ud];
            float4 t0 = make_float4(a0.x + a2.x, a0.y + a2.y, a0.z + a2.z, a0.w + a2.w);
            float4 t1 = make_float4(a0.x - a2.x, a0.y - a2.y, a0.z - a2.z, a0.w - a2.w);
            float4 t2v = make_float4(a1.x + a3.x, a1.y + a3.y, a1.z + a3.z, a1.w + a3.w);
            float4 t3 = make_float4(a1.x - a3.x, a1.y - a3.y, a1.z - a3.z, a1.w - a3.w);
            float2 w1 = tw[j * step];
            float2 w2 = cmulf(w1, w1);
            float2 w3 = cmulf(w2, w1);
            // y0 = t0 + t2
            *(float4*)&z[ua] = make_float4(t0.x + t2v.x, t0.y + t2v.y,
                                           t0.z + t2v.z, t0.w + t2v.w);
            {   // y1 = (t1 - i*t3) * w1
                float ax = t1.x + t3.y, ay = t1.y - t3.x;
                float bx = t1.z + t3.w, by = t1.w - t3.z;
                *(float4*)&z[ub_] = make_float4(ax * w1.x - ay * w1.y,
                                                ax * w1.y + ay * w1.x,
                                                bx * w1.x - by * w1.y,
                                                bx * w1.y + by * w1.x);
            }
            {   // y2 = (t0 - t2) * w2
                float ax = t0.x - t2v.x, ay = t0.y - t2v.y;
                float bx = t0.z - t2v.z, by = t0.w - t2v.w;
                *(float4*)&z[uc] = make_float4(ax * w2.x - ay * w2.y,
                                               ax * w2.y + ay * w2.x,
                                               bx * w2.x - by * w2.y,
                                               bx * w2.y + by * w2.x);
            }
            {   // y3 = (t1 + i*t3) * w3
                float ax = t1.x - t3.y, ay = t1.y + t3.x;
                float bx = t1.z - t3.w, by = t1.w + t3.z;
                *(float4*)&z[ud] = make_float4(ax * w3.x - ay * w3.y,
                                               ax * w3.y + ay * w3.x,
                                               bx * w3.x - by * w3.y,
                                               bx * w3.y + by * w3.x);
            }
            __syncthreads();
        }

        // ---- combine: X[k] += W4096^(t2*k)*Y[k]; X[4096-k] += conj(W)*Y[(1024-k)%1024] ----
        // Row of bin k=g+128j is rkg + off(j), off(j) = (j>>1) + 8*(j&1) (compile-time).
        // Mirror row: rkg2 + off(7-j) for g>0; off((8-j)&7) for g==0.
        float2 w     = tw2[(t2 << 7) + g];
        float2 wstep = tw[t2 << 5];
#pragma unroll
        for (int j = 0; j < 8; ++j) {
            const int offp = (j >> 1) + 8 * (j & 1);
            const int jm_a = (8 - j) & 7;          // g == 0 case
            const int jm_b = 7 - j;                // g >  0 case
            const int offm_a = (jm_a >> 1) + 8 * (jm_a & 1);
            const int offm_b = (jm_b >> 1) + 8 * (jm_b & 1);
            int rk  = rkg  + offp;
            int rk2 = rkg2 + (gz ? offm_a : offm_b);
            float2 Ya = z[(zu4(4 * rk  + dl2) << 1) | dlo];
            float2 Yb = z[(zu4(4 * rk2 + dl2) << 1) | dlo];
            X1[j].x += w.x * Ya.x - w.y * Ya.y;
            X1[j].y += w.x * Ya.y + w.y * Ya.x;
            Z4[j].x += w.x * Yb.x + w.y * Yb.y;   // conj(w) * Yb
            Z4[j].y += w.x * Yb.y - w.y * Yb.x;
            w = cmulf(w, wstep);
        }
    }

    // ---- unpack Qa/Qb, products, reduce over 8 d-lanes, atomic flush ----
#pragma unroll
    for (int j = 0; j < 8; ++j) {
        int k = g + 128 * j;
        float Ar = 0.5f * (X1[j].x + Z4[j].x);
        float Ai = 0.5f * (X1[j].y - Z4[j].y);
        float Br = 0.5f * (X1[j].y + Z4[j].y);
        float Bi = 0.5f * (Z4[j].x - X1[j].x);
        float da = Ar * Ar + Ai * Ai;
        float db = Br * Br + Bi * Bi;
        float cr = Ar * Br + Ai * Bi;
        float ci = Ar * Bi - Ai * Br;
        for (int msk = 1; msk < DLB; msk <<= 1) {
            da += __shfl_xor(da, msk);
            db += __shfl_xor(db, msk);
            cr += __shfl_xor(cr, msk);
            ci += __shfl_xor(ci, msk);
        }
        if (dl == 0) {
            atomicAdd(&ws[0 * NB * MBINS + bb * MBINS + k], da);
            atomicAdd(&ws[1 * NB * MBINS + bb * MBINS + k], db);
            atomicAdd(&ws[2 * NB * MBINS + bb * MBINS + k], cr);
            atomicAdd(&ws[3 * NB * MBINS + bb * MBINS + k], ci);
        }
    }
}

// Inverse: block = (b, dir). S = C/den (dir 0) or conj(C)/den (dir 1), padded to 4096,
// radix-4 IFFT (conj twiddles, digit-reversed output indexing), real part.
__global__ __launch_bounds__(512)
void cte_inv_kernel(const float* __restrict__ ws, float* __restrict__ out) {
    __shared__ float2 zz[4096];       // 32 KB
    __shared__ float2 tw[1024];       // tw[e] = exp(+2*pi*i*e/4096)
    const int tid = threadIdx.x;
    const int bb  = blockIdx.x >> 1;
    const int dir = blockIdx.x & 1;

    for (int i = tid; i < 1024; i += 512) {
        float s, c;
        sincosf(6.283185307179586f * (float)i * (1.0f / 4096.0f), &s, &c);
        tw[i] = make_float2(c, s);
    }
    for (int i = tid; i < 4096; i += 512) {
        float2 v = make_float2(0.f, 0.f);
        if (i < MBINS) {
            float den = ws[(dir ? 1 : 0) * NB * MBINS + bb * MBINS + i] + LMBDA;
            float cr  = ws[2 * NB * MBINS + bb * MBINS + i];
            float ci  = ws[3 * NB * MBINS + bb * MBINS + i];
            if (dir) ci = -ci;
            v = make_float2(cr / den, ci / den);
        }
        zz[i] = v;
    }
    __syncthreads();

#pragma unroll
    for (int st = 0; st < 6; ++st) {
        const int lgm  = 10 - 2 * st;     // m = 1024,256,64,16,4,1
        const int m    = 1 << lgm;
        const int step = 1024 >> lgm;     // 4096/(4m)
#pragma unroll
        for (int r = 0; r < 2; ++r) {
            int bf = r * 512 + tid;       // butterfly id [0,1024)
            int j  = bf & (m - 1);
            int i0 = ((bf >> lgm) << (lgm + 2)) + j;
            float2 a0 = zz[i0], a1 = zz[i0 + m], a2 = zz[i0 + 2 * m], a3 = zz[i0 + 3 * m];
            float2 t0  = caddf(a0, a2), t1v = csubf(a0, a2);
            float2 t2v = caddf(a1, a3), t3  = csubf(a1, a3);
            float2 y0 = caddf(t0, t2v);
            float2 y2 = csubf(t0, t2v);
            float2 y1 = make_float2(t1v.x - t3.y, t1v.y + t3.x);   // t1 + i*t3 (inverse)
            float2 y3 = make_float2(t1v.x + t3.y, t1v.y - t3.x);   // t1 - i*t3
            if (m > 1) {
                float2 w1 = tw[j * step];
                float2 w2 = cmulf(w1, w1);
                float2 w3 = cmulf(w2, w1);
                y1 = cmulf(y1, w1);
                y2 = cmulf(y2, w2);
                y3 = cmulf(y3, w3);
            }
            zz[i0] = y0; zz[i0 + m] = y1; zz[i0 + 2 * m] = y2; zz[i0 + 3 * m] = y3;
        }
        __syncthreads();
    }

    const float scale = 1.0f / 4096.0f;
    for (int t = tid; t < 4096; t += 512) {
        int rt = rev4_12(t);              // R[t] sits at digit-reversed slot
        float val = zz[rt].x * scale;
        int col = (dir == 0) ? (4095 - t) : (4096 + t);
        out[(size_t)bb * 8192 + col] = val;
    }
}

extern "C" void kernel_launch(void* const* d_in, const int* in_sizes, int n_in,
                              void* d_out, int out_size, void* d_ws, size_t ws_size,
                              hipStream_t stream) {
    const float* a = (const float*)d_in[0];
    const float* b = (const float*)d_in[1];
    // d_in[2] (offsets) only determines shapes; numerically unused.
    float* out = (float*)d_out;
    float* ws  = (float*)d_ws;

    hipMemsetAsync(d_ws, 0, 4 * NB * MBINS * sizeof(float), stream);
    cte_fwd_kernel<<<dim3(NB * (ND / DLB)), dim3(FWD_THREADS), 0, stream>>>(a, b, ws);
    cte_inv_kernel<<<dim3(NB * 2), dim3(512), 0, stream>>>(ws, out);
}